// Round 2
// baseline (55.201 us; speedup 1.0000x reference)
//
#include <hip/hip_runtime.h>
#include <hip/hip_bf16.h>
#include <math.h>

// Problem dims (fixed by reference setup_inputs)
#define B 8
#define NPTS 20000
#define M 1024
#define H 1024
#define BN_EPS 1e-5f

// BPS decomposition: 125 chunks * 160 points = 20000
#define BPS_CHUNK 160
#define BPS_NCHUNK 125
#define BPS_PAIRS (BPS_CHUNK / 2)

// layer1 decomposition
#define L1_MCHUNK 32
#define L1_NMCHUNK (M / L1_MCHUNK)   // 32

typedef float f2 __attribute__((ext_vector_type(2)));

// ---------------------------------------------------------------------------
// Kernel 1: BPS partial min over one N-chunk. NO atomics: each block writes
// its own partial-min slice pmin[(chunk*B + b)*M + m].
// Inner loop: packed fp32 (float2 = 2 points) * 4 basis/thread.
//   t_m = min_n (|p|^2 - 2 p.b)   ; dist2 = t_m + |b|^2, clamped >= 0.
// ---------------------------------------------------------------------------
__global__ __launch_bounds__(256) void bps_kernel(const float* __restrict__ x,
                                                  const float* __restrict__ basis,
                                                  float* __restrict__ pmin) {
    __shared__ f2 sx2[BPS_PAIRS], sy2[BPS_PAIRS], sz2[BPS_PAIRS], sw2[BPS_PAIRS];
    const int chunk = blockIdx.x;
    const int b = blockIdx.y;
    const int tid = threadIdx.x;
    const int n0 = chunk * BPS_CHUNK;
    const float* xb = x + (size_t)b * 3 * NPTS;

    if (tid < BPS_CHUNK) {
        float px = xb[n0 + tid];
        float py = xb[NPTS + n0 + tid];
        float pz = xb[2 * NPTS + n0 + tid];
        ((float*)sx2)[tid] = px;
        ((float*)sy2)[tid] = py;
        ((float*)sz2)[tid] = pz;
        ((float*)sw2)[tid] = px * px + py * py + pz * pz;
    }

    // 4 basis points per thread, pre-negated-doubled
    float nbx[4], nby[4], nbz[4], bb2[4];
#pragma unroll
    for (int k = 0; k < 4; ++k) {
        int m = tid + k * 256;
        float bx = basis[m * 3 + 0];
        float by = basis[m * 3 + 1];
        float bz = basis[m * 3 + 2];
        nbx[k] = -2.0f * bx;
        nby[k] = -2.0f * by;
        nbz[k] = -2.0f * bz;
        bb2[k] = bx * bx + by * by + bz * bz;
    }
    float acc[4] = {INFINITY, INFINITY, INFINITY, INFINITY};
    __syncthreads();

#pragma unroll 2
    for (int j = 0; j < BPS_PAIRS; ++j) {
        f2 X = sx2[j];
        f2 Y = sy2[j];
        f2 Z = sz2[j];
        f2 W = sw2[j];
#pragma unroll
        for (int k = 0; k < 4; ++k) {
            f2 s = W;
            f2 bx = {nbx[k], nbx[k]};
            f2 by = {nby[k], nby[k]};
            f2 bz = {nbz[k], nbz[k]};
            s = __builtin_elementwise_fma(X, bx, s);
            s = __builtin_elementwise_fma(Y, by, s);
            s = __builtin_elementwise_fma(Z, bz, s);
            acc[k] = fminf(acc[k], fminf(s.x, s.y));   // hope: v_min3_f32
        }
    }

#pragma unroll
    for (int k = 0; k < 4; ++k) {
        float v = fmaxf(acc[k] + bb2[k], 0.0f);        // clip(min,0) == min(clip)
        pmin[((size_t)chunk * B + b) * M + tid + k * 256] = v;
    }
}

// ---------------------------------------------------------------------------
// Kernel 2: reduce chunk-partials -> bn1 feature (LDS), then partial GEMV.
// grid = (H/256 = 4, 32 m-chunks) = 128 blocks, block 256.
// Writes non-atomic partials hpart[(mc*B + b)*H + i].
// ---------------------------------------------------------------------------
__global__ __launch_bounds__(256) void layer1_kernel(const float* __restrict__ pmin,
                                                     const float* __restrict__ g1,
                                                     const float* __restrict__ bb1,
                                                     const float* __restrict__ rm1,
                                                     const float* __restrict__ rv1,
                                                     const float* __restrict__ w1,
                                                     float* __restrict__ hpart) {
    __shared__ float fs[B][L1_MCHUNK];
    const int tid = threadIdx.x;
    const int i = blockIdx.x * 256 + tid;
    const int mc = blockIdx.y;
    const int m0 = mc * L1_MCHUNK;

    {
        int bb = tid >> 5;                  // 0..7
        int ml = tid & (L1_MCHUNK - 1);     // 0..31
        int m = m0 + ml;
        float v = INFINITY;
#pragma unroll 5
        for (int c = 0; c < BPS_NCHUNK; ++c) {
            v = fminf(v, pmin[((size_t)c * B + bb) * M + m]);
        }
        float f = sqrtf(v);
        float sc = g1[m] * rsqrtf(rv1[m] + BN_EPS);
        fs[bb][ml] = (f - rm1[m]) * sc + bb1[m];
    }
    __syncthreads();

    float acc[B] = {0, 0, 0, 0, 0, 0, 0, 0};
    const float* wrow = w1 + (size_t)i * M + m0;
#pragma unroll
    for (int ml = 0; ml < L1_MCHUNK; ml += 4) {
        float4 w = *reinterpret_cast<const float4*>(wrow + ml);
#pragma unroll
        for (int bb = 0; bb < B; ++bb) {
            float4 f = *reinterpret_cast<const float4*>(&fs[bb][ml]);
            acc[bb] = fmaf(f.x, w.x, acc[bb]);
            acc[bb] = fmaf(f.y, w.y, acc[bb]);
            acc[bb] = fmaf(f.z, w.z, acc[bb]);
            acc[bb] = fmaf(f.w, w.w, acc[bb]);
        }
    }
#pragma unroll
    for (int bb = 0; bb < B; ++bb) hpart[((size_t)mc * B + bb) * H + i] = acc[bb];
}

// ---------------------------------------------------------------------------
// Kernel 3: sum h partials + b1, relu, bn2, dot w2, + b2. grid = 8 blocks.
// ---------------------------------------------------------------------------
__global__ __launch_bounds__(256) void final_kernel(const float* __restrict__ hpart,
                                                    const float* __restrict__ b1,
                                                    const float* __restrict__ g2,
                                                    const float* __restrict__ bb2v,
                                                    const float* __restrict__ rm2,
                                                    const float* __restrict__ rv2,
                                                    const float* __restrict__ w2,
                                                    const float* __restrict__ b2,
                                                    float* __restrict__ out) {
    const int b = blockIdx.x;
    const int tid = threadIdx.x;
    float sum = 0.0f;
    for (int i = tid; i < H; i += 256) {
        float hs = 0.0f;
#pragma unroll 8
        for (int mc = 0; mc < L1_NMCHUNK; ++mc) {
            hs += hpart[((size_t)mc * B + b) * H + i];
        }
        float v = fmaxf(hs + b1[i], 0.0f);
        float sc = g2[i] * rsqrtf(rv2[i] + BN_EPS);
        v = (v - rm2[i]) * sc + bb2v[i];
        sum += v * w2[i];
    }
#pragma unroll
    for (int off = 32; off > 0; off >>= 1) sum += __shfl_down(sum, off, 64);
    __shared__ float wsum[4];
    if ((tid & 63) == 0) wsum[tid >> 6] = sum;
    __syncthreads();
    if (tid == 0) out[b] = wsum[0] + wsum[1] + wsum[2] + wsum[3] + b2[0];
}

// ---------------------------------------------------------------------------
extern "C" void kernel_launch(void* const* d_in, const int* in_sizes, int n_in,
                              void* d_out, int out_size, void* d_ws, size_t ws_size,
                              hipStream_t stream) {
    const float* x      = (const float*)d_in[0];
    const float* basis  = (const float*)d_in[1];
    const float* bn1_g  = (const float*)d_in[2];
    const float* bn1_b  = (const float*)d_in[3];
    const float* bn1_rm = (const float*)d_in[4];
    const float* bn1_rv = (const float*)d_in[5];
    const float* w1     = (const float*)d_in[6];
    const float* b1     = (const float*)d_in[7];
    const float* bn2_g  = (const float*)d_in[8];
    const float* bn2_b  = (const float*)d_in[9];
    const float* bn2_rm = (const float*)d_in[10];
    const float* bn2_rv = (const float*)d_in[11];
    const float* w2     = (const float*)d_in[12];
    const float* b2     = (const float*)d_in[13];
    float* out = (float*)d_out;

    // workspace layout (all fully rewritten every call — no cross-call state)
    float* pmin  = (float*)d_ws;                                   // 125*8*1024 f
    float* hpart = (float*)((char*)d_ws + (size_t)BPS_NCHUNK * B * M * 4); // 32*8*1024 f

    dim3 g1g(BPS_NCHUNK, B);
    bps_kernel<<<g1g, 256, 0, stream>>>(x, basis, pmin);

    dim3 g2g(H / 256, L1_NMCHUNK);
    layer1_kernel<<<g2g, 256, 0, stream>>>(pmin, bn1_g, bn1_b, bn1_rm, bn1_rv, w1, hpart);

    final_kernel<<<B, 256, 0, stream>>>(hpart, b1, bn2_g, bn2_b, bn2_rm, bn2_rv, w2, b2, out);
}